// Round 2
// baseline (305.760 us; speedup 1.0000x reference)
//
#include <hip/hip_runtime.h>

#define S 256
#define D 256
#define DFF 1024
#define NB 2

// ---------------- reductions ----------------
// 256-thread block: wave shfl reduce + 4-slot LDS combine
__device__ __forceinline__ float bsum(float v, float* red) {
#pragma unroll
    for (int off = 32; off; off >>= 1) v += __shfl_xor(v, off, 64);
    __syncthreads();
    if (!(threadIdx.x & 63)) red[threadIdx.x >> 6] = v;
    __syncthreads();
    return red[0] + red[1] + red[2] + red[3];
}
// 512-thread block, two independent 256-thread groups (grp = tid>>8); red[8]
__device__ __forceinline__ float gsum(float v, float* red, int grp) {
#pragma unroll
    for (int off = 32; off; off >>= 1) v += __shfl_xor(v, off, 64);
    __syncthreads();
    if (!(threadIdx.x & 63)) red[threadIdx.x >> 6] = v;
    __syncthreads();
    int b0 = grp * 4;
    return red[b0] + red[b0 + 1] + red[b0 + 2] + red[b0 + 3];
}
__device__ __forceinline__ float gmax(float v, float* red, int grp) {
#pragma unroll
    for (int off = 32; off; off >>= 1) v = fmaxf(v, __shfl_xor(v, off, 64));
    __syncthreads();
    if (!(threadIdx.x & 63)) red[threadIdx.x >> 6] = v;
    __syncthreads();
    int b0 = grp * 4;
    return fmaxf(fmaxf(red[b0], red[b0 + 1]), fmaxf(red[b0 + 2], red[b0 + 3]));
}

// ---------- K1: embedding + positional encoding (grid 512, block 256) ----------
__global__ __launch_bounds__(256) void k_embed(
    const int* __restrict__ x, const float* __restrict__ mask,
    const int* __restrict__ use_pos, const float* __restrict__ pos_enc,
    const float* __restrict__ emb_W, const float* __restrict__ emb_b,
    float* __restrict__ h)
{
    __shared__ float red[4];
    int r = blockIdx.x, d = threadIdx.x;
    int b = r >> 8, s = r & 255;
    float mv = (d <= s) ? (1.0f - mask[b * S + d]) : 0.0f;
    float cum = bsum(mv, red);
    int idx = (int)(cum + 0.5f);
    int xv = x[r];
    float acc = emb_b[d];
#pragma unroll
    for (int k = 0; k < 16; k++)
        if ((xv >> k) & 1) acc += emb_W[k * D + d];
    acc *= 16.0f;
    if (use_pos[0]) acc += pos_enc[idx * D + d];
    h[r * D + d] = acc;
}

// ---------- K2: qkv = h@wW+wb ; qa' = qkv@W1a + b1 ; qb = qkv@W1b ----------
// grid 256 (2 parallel rows), block 512 (row = tid>>8, col = tid&255)
__global__ __launch_bounds__(512) void k_qkv(
    const float* __restrict__ h, const float* __restrict__ wW, const float* __restrict__ wb,
    const float* __restrict__ nnW1, const float* __restrict__ nnb1,
    float* __restrict__ qkv, float* __restrict__ qa, float* __restrict__ qb)
{
    __shared__ float hs[2][256];
    __shared__ float qs[2][256];
    int r0 = blockIdx.x * 2;
    int row = threadIdx.x >> 8;
    int c = threadIdx.x & 255;
    hs[row][c] = h[(r0 + row) * D + c];
    __syncthreads();
    float acc = wb[c];
#pragma unroll 8
    for (int k = 0; k < D; k++) acc = fmaf(hs[row][k], wW[k * D + c], acc);
    qkv[(r0 + row) * D + c] = acc;
    qs[row][c] = acc;
    __syncthreads();
    float a = nnb1[c], bb = 0.f;
#pragma unroll 4
    for (int k = 0; k < D; k++) {
        float q = qs[row][k];
        a  = fmaf(q, nnW1[k * D + c], a);
        bb = fmaf(q, nnW1[(k + D) * D + c], bb);
    }
    qa[(r0 + row) * D + c] = a;
    qb[(r0 + row) * D + c] = bb;
}

// ---------- K3: g[b,i,j] = sum_h relu(qa'[i,h]+qb[j,h]) * w2[h] ----------
// grid 256 (2 i-rows), block 512 (j = tid&255, h-half = tid>>8)
__global__ __launch_bounds__(512) void k_g(
    const float* __restrict__ qa, const float* __restrict__ qb,
    const float* __restrict__ w2, float* __restrict__ g)
{
    __shared__ float qa_s[2][256];
    __shared__ float w2_s[256];
    __shared__ float tmp[2][256];
    int b = blockIdx.x >> 7;
    int i0 = (blockIdx.x & 127) * 2;
    int j = threadIdx.x & 255;
    int half = threadIdx.x >> 8;
    if (threadIdx.x < 512) {
        int rr = threadIdx.x >> 8, cc = threadIdx.x & 255;
        qa_s[rr][cc] = qa[(b * S + i0 + rr) * D + cc];
    }
    if (threadIdx.x < 256) w2_s[threadIdx.x] = w2[threadIdx.x];
    __syncthreads();
    float acc0 = 0.f, acc1 = 0.f;
    const float4* qbr = (const float4*)(qb + (b * S + j) * D + half * 128);
    const int hb = half * 128;
#pragma unroll 4
    for (int q = 0; q < 32; q++) {
        float4 v4 = qbr[q];
        float qv[4] = {v4.x, v4.y, v4.z, v4.w};
#pragma unroll
        for (int e = 0; e < 4; e++) {
            int hh = hb + q * 4 + e;
            float wv = w2_s[hh];
            acc0 = fmaf(fmaxf(qa_s[0][hh] + qv[e], 0.f), wv, acc0);
            acc1 = fmaf(fmaxf(qa_s[1][hh] + qv[e], 0.f), wv, acc1);
        }
    }
    if (half) { tmp[0][j] = acc0; tmp[1][j] = acc1; }
    __syncthreads();
    if (!half) {
        g[(b * S + i0 + 0) * S + j] = acc0 + tmp[0][j];
        g[(b * S + i0 + 1) * S + j] = acc1 + tmp[1][j];
    }
}

// ---------- K4: softmax(g+gT+2b2+mask) @ qkv -> proj -> +h -> LN1 ----------
// grid 256 (2 parallel rows), block 512
__global__ __launch_bounds__(512) void k_attn_proj_ln(
    const float* __restrict__ g, const float* __restrict__ mask,
    const float* __restrict__ b2p, const float* __restrict__ qkv,
    const float* __restrict__ outW, const float* __restrict__ outb,
    const float* __restrict__ h, const float* __restrict__ lng, const float* __restrict__ lnb,
    float* __restrict__ o1)
{
    __shared__ float attn_s[2][256];
    __shared__ float as[2][256];
    __shared__ float red[8];
    int r0 = blockIdx.x * 2;
    int b = r0 >> 8;
    int grp = threadIdx.x >> 8;
    int t = threadIdx.x & 255;
    int i = (r0 & 255) + grp;

    float sv = g[(b * S + i) * S + t] + g[(b * S + t) * S + i]
             + 2.0f * b2p[0] + mask[b * S + t] * (-1e9f);
    float m = gmax(sv, red, grp);
    float e = __expf(sv - m);
    float inv = 1.0f / gsum(e, red, grp);
    attn_s[grp][t] = e * inv;
    __syncthreads();

    float acc = 0.f;
    const float* qkvb = qkv + (size_t)b * S * D + t;
#pragma unroll 8
    for (int jj = 0; jj < S; jj++) acc = fmaf(attn_s[grp][jj], qkvb[jj * D], acc);
    as[grp][t] = acc;
    __syncthreads();

    float accp = outb[t];
#pragma unroll 8
    for (int k = 0; k < D; k++) accp = fmaf(as[grp][k], outW[k * D + t], accp);

    float v = h[(r0 + grp) * D + t] + accp;   // RES=1, ALT=1
    float mu = gsum(v, red, grp) * (1.0f / 256.0f);
    float dv = v - mu;
    float var = gsum(dv * dv, red, grp) * (1.0f / 256.0f);
    o1[(r0 + grp) * D + t] = dv * rsqrtf(var + 1e-6f) * lng[t] + lnb[t];
}

// ---------- K5: f1 = relu(o1 @ ffnW1 + ffnb1) ----------
// grid (128, 4); block 512: grp = tid>>8 handles rows r0+2*grp, +1; col tile 256
__global__ __launch_bounds__(512) void k_ffn1(
    const float* __restrict__ o1, const float* __restrict__ W1, const float* __restrict__ b1,
    float* __restrict__ f1)
{
    __shared__ float as[4][256];
    int r0 = blockIdx.x * 4;
    int c = blockIdx.y * 256 + (threadIdx.x & 255);
    int grp = threadIdx.x >> 8;
    for (int idx = threadIdx.x; idx < 4 * 256; idx += 512)
        as[idx >> 8][idx & 255] = o1[(r0 + (idx >> 8)) * D + (idx & 255)];
    __syncthreads();
    float bv = b1[c];
    float acc0 = bv, acc1 = bv;
    int ra = grp * 2, rb = grp * 2 + 1;
#pragma unroll 8
    for (int k = 0; k < D; k++) {
        float w = W1[k * DFF + c];
        acc0 = fmaf(as[ra][k], w, acc0);
        acc1 = fmaf(as[rb][k], w, acc1);
    }
    f1[(r0 + ra) * DFF + c] = fmaxf(acc0, 0.f);
    f1[(r0 + rb) * DFF + c] = fmaxf(acc1, 0.f);
}

// ---------- K6: split-K(2) partials of f1 @ ffnW2 (+b2 on split 0) ----------
// grid (128, 2); block 512: grp = tid>>8 handles rows r0+2*grp, +1; K-half 512
__global__ __launch_bounds__(512) void k_ffn2p(
    const float* __restrict__ f1, const float* __restrict__ W2, const float* __restrict__ b2,
    float* __restrict__ part)
{
    __shared__ float fs[4][512];
    int r0 = blockIdx.x * 4;
    int kh = blockIdx.y;
    int c = threadIdx.x & 255;
    int grp = threadIdx.x >> 8;
    for (int idx = threadIdx.x; idx < 4 * 512; idx += 512) {
        int rr = idx >> 9, cc = idx & 511;
        fs[rr][cc] = f1[(r0 + rr) * DFF + kh * 512 + cc];
    }
    __syncthreads();
    float acc0 = 0.f, acc1 = 0.f;
    if (kh == 0) { float bv = b2[c]; acc0 = bv; acc1 = bv; }
    int ra = grp * 2, rb = grp * 2 + 1;
    const float* w = W2 + (size_t)(kh * 512) * D + c;
#pragma unroll 8
    for (int k = 0; k < 512; k++) {
        float wv = w[(size_t)k * D];
        acc0 = fmaf(fs[ra][k], wv, acc0);
        acc1 = fmaf(fs[rb][k], wv, acc1);
    }
    part[((size_t)kh * 512 + r0 + ra) * D + c] = acc0;
    part[((size_t)kh * 512 + r0 + rb) * D + c] = acc1;
}

// ---------- K7: h' = LN2(o1 + sum partials) (grid 512, block 256) ----------
__global__ __launch_bounds__(256) void k_ffn2_ln(
    const float* __restrict__ part, const float* __restrict__ o1,
    const float* __restrict__ lng, const float* __restrict__ lnb,
    float* __restrict__ hout)
{
    __shared__ float red[4];
    int r = blockIdx.x;
    int c = threadIdx.x;
    float f = part[(size_t)r * D + c] + part[((size_t)512 + r) * D + c];
    float v = o1[r * D + c] + f;   // RES=1, ALT=1
    float mu = bsum(v, red) * (1.0f / 256.0f);
    float dv = v - mu;
    float var = bsum(dv * dv, red) * (1.0f / 256.0f);
    hout[r * D + c] = dv * rsqrtf(var + 1e-6f) * lng[c] + lnb[c];
}

extern "C" void kernel_launch(void* const* d_in, const int* in_sizes, int n_in,
                              void* d_out, int out_size, void* d_ws, size_t ws_size,
                              hipStream_t stream)
{
    const int*   x       = (const int*)d_in[0];
    const float* mask    = (const float*)d_in[1];
    const int*   use_pos = (const int*)d_in[3];
    const float* pos_enc = (const float*)d_in[4];
    const float* emb_W   = (const float*)d_in[5];
    const float* emb_b   = (const float*)d_in[6];
    const float* nn_W1   = (const float*)d_in[7];
    const float* nn_b1   = (const float*)d_in[8];
    const float* nn_W2   = (const float*)d_in[9];
    const float* nn_b2   = (const float*)d_in[10];
    const float* w_W     = (const float*)d_in[11];
    const float* w_b     = (const float*)d_in[12];
    const float* out_W   = (const float*)d_in[13];
    const float* out_b   = (const float*)d_in[14];
    const float* ffn_W1  = (const float*)d_in[15];
    const float* ffn_b1  = (const float*)d_in[16];
    const float* ffn_W2  = (const float*)d_in[17];
    const float* ffn_b2  = (const float*)d_in[18];
    const float* ln1_g   = (const float*)d_in[19];
    const float* ln1_b   = (const float*)d_in[20];
    const float* ln2_g   = (const float*)d_in[21];
    const float* ln2_b   = (const float*)d_in[22];

    float* ws   = (float*)d_ws;
    float* h    = ws;                 // 131072
    float* qkv  = ws + 131072;
    float* qa   = ws + 262144;
    float* qb   = ws + 393216;
    float* g    = ws + 524288;
    float* o1   = ws + 655360;
    float* f1   = ws + 786432;        // 524288
    float* part = ws + 1310720;       // 262144

    k_embed<<<512, 256, 0, stream>>>(x, mask, use_pos, pos_enc, emb_W, emb_b, h);

    for (int l = 0; l < 2; l++) {
        k_qkv<<<256, 512, 0, stream>>>(h, w_W + l * D * D, w_b + l * D,
                                       nn_W1, nn_b1, qkv, qa, qb);
        k_g<<<256, 512, 0, stream>>>(qa, qb, nn_W2, g);
        k_attn_proj_ln<<<256, 512, 0, stream>>>(g, mask, nn_b2, qkv,
                                                out_W + l * D * D, out_b + l * D,
                                                h, ln1_g + l * D, ln1_b + l * D, o1);
        k_ffn1<<<dim3(128, 4), 512, 0, stream>>>(o1, ffn_W1 + l * D * DFF,
                                                 ffn_b1 + l * DFF, f1);
        k_ffn2p<<<dim3(128, 2), 512, 0, stream>>>(f1, ffn_W2 + l * DFF * D,
                                                  ffn_b2 + l * D, part);
        float* hout = (l == 1) ? (float*)d_out : h;
        k_ffn2_ln<<<512, 256, 0, stream>>>(part, o1, ln2_g + l * D, ln2_b + l * D, hout);
    }
}